// Round 9
// baseline (261.051 us; speedup 1.0000x reference)
//
#include <hip/hip_runtime.h>

#define MESH  128
#define MESH2 16384
#define MESH3 2097152
#define NPART MESH3
#define TILE  16
#define LDP   (TILE + 1)
#define LDP2  129     // full-plane pad: row stride 129 float2
#define CAP   6
#define BSTRIDE 1536   // slots per bucket region (mean 1024, >15 sigma headroom)
typedef unsigned int u32;
typedef unsigned short u16;
typedef unsigned long long u64;

__device__ __forceinline__ float2 cmul(float2 a, float2 b) {
    return make_float2(a.x * b.x - a.y * b.y, a.x * b.y + a.y * b.x);
}
__device__ __forceinline__ float2 cadd(float2 a, float2 b) {
    return make_float2(a.x + b.x, a.y + b.y);
}
__device__ __forceinline__ float2 csub(float2 a, float2 b) {
    return make_float2(a.x - b.x, a.y - b.y);
}
__device__ __forceinline__ u16 f2bf(float x) {
    u32 b = __float_as_uint(x);
    return (u16)((b + 0x7FFFu + ((b >> 16) & 1u)) >> 16);   // RNE
}
__device__ __forceinline__ float bf2f(u16 h) {
    return __uint_as_float(((u32)h) << 16);
}

// ---------------- radix-4 128-point FFT core (tile version, fft_x_mega) ------
__device__ __forceinline__ void fft128_fwd_lds(float2 (*__restrict__ s)[LDP],
                                               const float2* __restrict__ tw,
                                               int l, int bb) {
    #pragma unroll
    for (int pr = 0; pr < 3; ++pr) {
        const int st = 2 * pr;
        const int logq = 5 - st;
        const int q = 1 << logq;
        const int j = bb & (q - 1);
        const int g = bb >> logq;
        const int i0 = (g << (logq + 2)) + j;
        const float2 x0 = s[i0][l], x1 = s[i0 + q][l];
        const float2 x2 = s[i0 + 2 * q][l], x3 = s[i0 + 3 * q][l];
        const int m = j << st;
        const float2 wA = tw[m], wA2 = tw[m + 32], wB = tw[2 * m];
        const float2 u0 = cadd(x0, x2), u2 = cmul(csub(x0, x2), wA);
        const float2 u1 = cadd(x1, x3), u3 = cmul(csub(x1, x3), wA2);
        s[i0][l]         = cadd(u0, u1);
        s[i0 + q][l]     = cmul(csub(u0, u1), wB);
        s[i0 + 2 * q][l] = cadd(u2, u3);
        s[i0 + 3 * q][l] = cmul(csub(u2, u3), wB);
        __syncthreads();
    }
    #pragma unroll
    for (int itn = 0; itn < 2; ++itn) {
        const int i0 = (bb + (itn << 5)) << 1;
        const float2 x0 = s[i0][l], x1 = s[i0 + 1][l];
        s[i0][l]     = cadd(x0, x1);
        s[i0 + 1][l] = csub(x0, x1);
    }
}

// Dual-array DIT inverse (interleaved for ILP) — used by fft_x_mega.
__device__ __forceinline__ void fft128_inv_lds_dual(float2 (*__restrict__ SA)[LDP],
                                                    float2 (*__restrict__ SB)[LDP],
                                                    const float2* __restrict__ tw,
                                                    int l, int bb) {
    #pragma unroll
    for (int pr = 0; pr < 3; ++pr) {
        const int st = 2 * pr;
        const int p = 1 << st;
        const int j = bb & (p - 1);
        const int g = bb >> st;
        const int i0 = (g << (st + 2)) + j;
        const float2 wA = tw[j << (6 - st)];
        const int mB = j << (5 - st);
        const float2 wB = tw[mB], wB2 = tw[mB + 32];
        {
            const float2 x0 = SA[i0][l], x1 = SA[i0 + p][l];
            const float2 x2 = SA[i0 + 2 * p][l], x3 = SA[i0 + 3 * p][l];
            const float2 a1 = cmul(x1, wA), a3 = cmul(x3, wA);
            const float2 u0 = cadd(x0, a1), u1 = csub(x0, a1);
            const float2 u2 = cadd(x2, a3), u3 = csub(x2, a3);
            const float2 b2 = cmul(u2, wB), b3 = cmul(u3, wB2);
            SA[i0][l]         = cadd(u0, b2);
            SA[i0 + p][l]     = cadd(u1, b3);
            SA[i0 + 2 * p][l] = csub(u0, b2);
            SA[i0 + 3 * p][l] = csub(u1, b3);
        }
        {
            const float2 x0 = SB[i0][l], x1 = SB[i0 + p][l];
            const float2 x2 = SB[i0 + 2 * p][l], x3 = SB[i0 + 3 * p][l];
            const float2 a1 = cmul(x1, wA), a3 = cmul(x3, wA);
            const float2 u0 = cadd(x0, a1), u1 = csub(x0, a1);
            const float2 u2 = cadd(x2, a3), u3 = csub(x2, a3);
            const float2 b2 = cmul(u2, wB), b3 = cmul(u3, wB2);
            SB[i0][l]         = cadd(u0, b2);
            SB[i0 + p][l]     = cadd(u1, b3);
            SB[i0 + 2 * p][l] = csub(u0, b2);
            SB[i0 + 3 * p][l] = csub(u1, b3);
        }
        __syncthreads();
    }
    #pragma unroll
    for (int itn = 0; itn < 2; ++itn) {
        const int b = bb + (itn << 5);
        const float2 w = tw[b];
        {
            const float2 u = SA[b][l];
            const float2 v = cmul(SA[b + 64][l], w);
            SA[b][l]      = cadd(u, v);
            SA[b + 64][l] = csub(u, v);
        }
        {
            const float2 u = SB[b][l];
            const float2 v = cmul(SB[b + 64][l], w);
            SB[b][l]      = cadd(u, v);
            SB[b + 64][l] = csub(u, v);
        }
    }
}

// ------- fused halo-merge + forward z-FFT + forward y-FFT, full plane --------
// 128 blocks (one per x), 1024 threads. LDS: 128 x 129 float2 = 129 KiB.
// ST: 2048 tiles x 1920 floats, tile layout [hx:5][hy:3][z:128].
__global__ __launch_bounds__(1024) void fft_zy_fwd_mega(const float* __restrict__ ST,
                                                        float2* __restrict__ A) {
    __shared__ float2 s[MESH][LDP2];
    __shared__ float2 tw[64];
    const int t = threadIdx.x;
    if (t < 64) {
        float sv, cv;
        sincospif(-(float)t / 64.0f, &sv, &cv);
        tw[t] = make_float2(cv, sv);      // e^{-i pi m/64}
    }
    const int x = blockIdx.x;
    const int tx = x >> 2, hx = x & 3;
    const int txm = (tx + 31) & 31;
    // merge-load: s[y][z]
    for (int i = t; i < MESH * MESH; i += 1024) {
        const int y = i >> 7, z = i & 127;
        const int ty = y >> 1, hy = y & 1;
        float v = ST[((tx << 6) | ty) * 1920 + ((hx * 3 + hy) << 7) + z];
        const int tym = (ty + 63) & 63;
        if (hx == 0)
            v += ST[((txm << 6) | ty) * 1920 + ((12 + hy) << 7) + z];
        if (hy == 0) {
            v += ST[((tx << 6) | tym) * 1920 + ((hx * 3 + 2) << 7) + z];
            if (hx == 0)
                v += ST[((txm << 6) | tym) * 1920 + (14 << 7) + z];
        }
        s[y][z] = make_float2(v, 0.0f);
    }
    __syncthreads();

    const int wrk = t >> 7;           // [0,8)
    // ---- phase 1: forward DIF along z (second index) ----
    const int row = t & 127;
    #pragma unroll
    for (int pr = 0; pr < 3; ++pr) {
        const int st = 2 * pr;
        const int logq = 5 - st;
        const int q = 1 << logq;
        #pragma unroll
        for (int n = 0; n < 4; ++n) {
            const int bb = wrk | (n << 3);
            const int j = bb & (q - 1);
            const int g = bb >> logq;
            const int i0 = (g << (logq + 2)) + j;
            const int m = j << st;
            const float2 wA = tw[m], wA2 = tw[m + 32], wB = tw[2 * m];
            const float2 x0 = s[row][i0], x1 = s[row][i0 + q];
            const float2 x2 = s[row][i0 + 2 * q], x3 = s[row][i0 + 3 * q];
            const float2 u0 = cadd(x0, x2), u2 = cmul(csub(x0, x2), wA);
            const float2 u1 = cadd(x1, x3), u3 = cmul(csub(x1, x3), wA2);
            s[row][i0]         = cadd(u0, u1);
            s[row][i0 + q]     = cmul(csub(u0, u1), wB);
            s[row][i0 + 2 * q] = cadd(u2, u3);
            s[row][i0 + 3 * q] = cmul(csub(u2, u3), wB);
        }
        __syncthreads();
    }
    #pragma unroll
    for (int n = 0; n < 8; ++n) {
        const int i0 = (wrk | (n << 3)) << 1;
        const float2 x0 = s[row][i0], x1 = s[row][i0 + 1];
        s[row][i0]     = cadd(x0, x1);
        s[row][i0 + 1] = csub(x0, x1);
    }
    __syncthreads();

    // ---- phase 2: forward DIF along y (first index) ----
    const int col = t & 127;
    #pragma unroll
    for (int pr = 0; pr < 3; ++pr) {
        const int st = 2 * pr;
        const int logq = 5 - st;
        const int q = 1 << logq;
        #pragma unroll
        for (int n = 0; n < 4; ++n) {
            const int bb = wrk | (n << 3);
            const int j = bb & (q - 1);
            const int g = bb >> logq;
            const int i0 = (g << (logq + 2)) + j;
            const int m = j << st;
            const float2 wA = tw[m], wA2 = tw[m + 32], wB = tw[2 * m];
            const float2 x0 = s[i0][col], x1 = s[i0 + q][col];
            const float2 x2 = s[i0 + 2 * q][col], x3 = s[i0 + 3 * q][col];
            const float2 u0 = cadd(x0, x2), u2 = cmul(csub(x0, x2), wA);
            const float2 u1 = cadd(x1, x3), u3 = cmul(csub(x1, x3), wA2);
            s[i0][col]         = cadd(u0, u1);
            s[i0 + q][col]     = cmul(csub(u0, u1), wB);
            s[i0 + 2 * q][col] = cadd(u2, u3);
            s[i0 + 3 * q][col] = cmul(csub(u2, u3), wB);
        }
        __syncthreads();
    }
    #pragma unroll
    for (int n = 0; n < 8; ++n) {
        const int i0 = (wrk | (n << 3)) << 1;
        const float2 x0 = s[i0][col], x1 = s[i0 + 1][col];
        s[i0][col]     = cadd(x0, x1);
        s[i0 + 1][col] = csub(x0, x1);
    }
    __syncthreads();

    const int gbase = x * MESH2;
    for (int i = t; i < MESH * MESH; i += 1024)
        A[gbase + i] = s[i >> 7][i & 127];
}

// ------- fused inverse y + inverse z + bf16 pack, full (y,z) plane in LDS ----
// 256 blocks: [0,128) = A plane x -> Abf bf16x2, [128,256) = B plane x -> Brl.
__global__ __launch_bounds__(1024) void fft_yz_inv_mega(const float2* __restrict__ A,
                                                        const float2* __restrict__ B,
                                                        u32* __restrict__ Abf,
                                                        u16* __restrict__ Brl) {
    __shared__ float2 s[MESH][LDP2];
    __shared__ float2 tw[64];
    const int t = threadIdx.x;
    if (t < 64) {
        float sv, cv;
        sincospif(-(float)t / 64.0f, &sv, &cv);
        tw[t] = make_float2(cv, -sv);     // e^{+i pi m/64}
    }
    const bool isB = blockIdx.x >= 128;
    const int x = blockIdx.x & 127;
    const float2* __restrict__ in = isB ? B : A;
    const int gbase = x * MESH2;
    for (int i = t; i < MESH * MESH; i += 1024)
        s[i >> 7][i & 127] = in[gbase + i];      // s[y][z]
    __syncthreads();

    const int col = t & 127;          // phase-1: z column
    const int wrk = t >> 7;           // [0,8)

    // ---- phase 1: inverse DIT along y (first index) ----
    #pragma unroll
    for (int pr = 0; pr < 3; ++pr) {
        const int st = 2 * pr;
        const int p = 1 << st;
        #pragma unroll
        for (int n = 0; n < 4; ++n) {
            const int bb = wrk | (n << 3);               // [0,32)
            const int j = bb & (p - 1);
            const int g = bb >> st;
            const int i0 = (g << (st + 2)) + j;
            const float2 wA = tw[j << (6 - st)];
            const int mB = j << (5 - st);
            const float2 wB = tw[mB], wB2 = tw[mB + 32];
            const float2 x0 = s[i0][col], x1 = s[i0 + p][col];
            const float2 x2 = s[i0 + 2 * p][col], x3 = s[i0 + 3 * p][col];
            const float2 a1 = cmul(x1, wA), a3 = cmul(x3, wA);
            const float2 u0 = cadd(x0, a1), u1 = csub(x0, a1);
            const float2 u2 = cadd(x2, a3), u3 = csub(x2, a3);
            const float2 b2 = cmul(u2, wB), b3 = cmul(u3, wB2);
            s[i0][col]         = cadd(u0, b2);
            s[i0 + p][col]     = cadd(u1, b3);
            s[i0 + 2 * p][col] = csub(u0, b2);
            s[i0 + 3 * p][col] = csub(u1, b3);
        }
        __syncthreads();
    }
    #pragma unroll
    for (int n = 0; n < 8; ++n) {
        const int b = wrk | (n << 3);                    // [0,64)
        const float2 w = tw[b];
        const float2 u = s[b][col];
        const float2 v = cmul(s[b + 64][col], w);
        s[b][col]      = cadd(u, v);
        s[b + 64][col] = csub(u, v);
    }
    __syncthreads();

    // ---- phase 2: inverse DIT along z (second index) ----
    const int row = t & 127;          // phase-2: y row
    #pragma unroll
    for (int pr = 0; pr < 3; ++pr) {
        const int st = 2 * pr;
        const int p = 1 << st;
        #pragma unroll
        for (int n = 0; n < 4; ++n) {
            const int bb = wrk | (n << 3);
            const int j = bb & (p - 1);
            const int g = bb >> st;
            const int i0 = (g << (st + 2)) + j;
            const float2 wA = tw[j << (6 - st)];
            const int mB = j << (5 - st);
            const float2 wB = tw[mB], wB2 = tw[mB + 32];
            const float2 x0 = s[row][i0], x1 = s[row][i0 + p];
            const float2 x2 = s[row][i0 + 2 * p], x3 = s[row][i0 + 3 * p];
            const float2 a1 = cmul(x1, wA), a3 = cmul(x3, wA);
            const float2 u0 = cadd(x0, a1), u1 = csub(x0, a1);
            const float2 u2 = cadd(x2, a3), u3 = csub(x2, a3);
            const float2 b2 = cmul(u2, wB), b3 = cmul(u3, wB2);
            s[row][i0]         = cadd(u0, b2);
            s[row][i0 + p]     = cadd(u1, b3);
            s[row][i0 + 2 * p] = csub(u0, b2);
            s[row][i0 + 3 * p] = csub(u1, b3);
        }
        __syncthreads();
    }
    #pragma unroll
    for (int n = 0; n < 8; ++n) {
        const int b = wrk | (n << 3);
        const float2 w = tw[b];
        const float2 u = s[row][b];
        const float2 v = cmul(s[row][b + 64], w);
        s[row][b]      = cadd(u, v);
        s[row][b + 64] = csub(u, v);
    }
    __syncthreads();

    if (isB) {
        for (int i = t; i < MESH * MESH; i += 1024)
            Brl[gbase + i] = f2bf(s[i >> 7][i & 127].x);
    } else {
        for (int i = t; i < MESH * MESH; i += 1024) {
            const float2 v = s[i >> 7][i & 127];
            Abf[gbase + i] = (u32)f2bf(v.x) | ((u32)f2bf(v.y) << 16);
        }
    }
}

// Fused: forward x-FFT (DIF) -> filter -> inverse x-FFT (DIT) on A and B lines.
__global__ __launch_bounds__(512) void fft_x_mega(float2* __restrict__ A,
                                                  float2* __restrict__ B) {
    __shared__ float2 SA[MESH][LDP];
    __shared__ float2 SB[MESH][LDP];
    __shared__ float2 twf[64];
    __shared__ float2 twi[64];
    const int t = threadIdx.x;
    if (t < 64) {
        float sv, cv;
        sincospif(-(float)t / 64.0f, &sv, &cv);
        twf[t] = make_float2(cv, sv);
        twi[t] = make_float2(cv, -sv);
    }
    const int cy = blockIdx.x >> 3;
    const int z0 = (blockIdx.x & 7) * TILE;
    const int base = cy * MESH + z0;

    for (int i = t; i < MESH * TILE; i += 512) {
        const int l = i & 15, e = i >> 4;
        SA[e][l] = A[base + e * MESH2 + l];
    }
    __syncthreads();

    const int l  = t & 15;
    const int bb = t >> 4;
    fft128_fwd_lds(SA, twf, l, bb);
    __syncthreads();

    const int jy = (int)(__brev((unsigned)cy) >> 25);
    const float c = 6.28318530717958647692f / 128.0f;
    const float ky = c * (float)(jy < 64 ? jy : jy - 128);
    for (int i = t; i < MESH * TILE; i += 512) {
        const int e = i & 127, ll = i >> 7;
        const int jx = (int)(__brev((unsigned)e) >> 25);
        const int jz = (int)(__brev((unsigned)(z0 + ll)) >> 25);
        const float kx = c * (float)(jx < 64 ? jx : jx - 128);
        const float kz = c * (float)(jz < 64 ? jz : jz - 128);
        const float kk = kx * kx + ky * ky + kz * kz;
        float2 a = SA[e][ll];
        float2 av = make_float2(0.f, 0.f), bv = make_float2(0.f, 0.f);
        if (kk > 0.0f) {
            const float inv_kk = 1.0f / kk;
            const float rng = __expf(-0.09f * inv_kk - kk * kk);  // KL^2=0.09, KS^4=1
            const float sc  = -inv_kk * rng * (1.0f / 2097152.0f);
            const float pr = a.x * sc, pi = a.y * sc;
            av = make_float2(ky * pr + kx * pi, ky * pi - kx * pr);
            bv = make_float2(kz * pi, -kz * pr);
        }
        SA[e][ll] = av;
        SB[e][ll] = bv;
    }
    __syncthreads();

    fft128_inv_lds_dual(SA, SB, twi, l, bb);
    __syncthreads();

    for (int i = t; i < MESH * TILE; i += 512) {
        const int l2 = i & 15, e = i >> 4;
        A[base + e * MESH2 + l2] = SA[e][l2];
        B[base + e * MESH2 + l2] = SB[e][l2];
    }
}

// ---------------- particle binning: 2048 buckets (4x2 columns) ----------------

__device__ __forceinline__ int bucket_of(float px, float py) {
    const int ix = ((int)floorf(px)) & 127;
    const int iy = ((int)floorf(py)) & 127;
    return ((ix >> 2) << 6) | (iy >> 1);
}

__device__ __forceinline__ u64 make_rec(float px, float py, float pz, int n) {
    const float fxx = floorf(px), fyy = floorf(py), fzz = floorf(pz);
    const int ix = ((int)fxx) & 127, iy = ((int)fyy) & 127, iz = ((int)fzz) & 127;
    const u32 qx = (u32)((px - fxx) * 1024.0f);
    const u32 qy = (u32)((py - fyy) * 1024.0f);
    const u32 qz = (u32)((pz - fzz) * 1024.0f);
    return (u64)iz | ((u64)(ix & 3) << 7) | ((u64)(iy & 1) << 9)
         | ((u64)qx << 11) | ((u64)qy << 21) | ((u64)qz << 31)
         | ((u64)(u32)n << 41);
}

// Fused hist+scan+scatter: one pass. Each bucket owns a fixed BSTRIDE region
// of S; a block reserves its span with one global atomicAdd per non-empty
// bucket. Also streams the pos copy to out.
__global__ __launch_bounds__(1024) void bin_kernel(const float* __restrict__ pos,
                                                   u32* __restrict__ gcnt,
                                                   u64* __restrict__ S,
                                                   float4* __restrict__ outp) {
    __shared__ u32 h[2048];
    const int t = threadIdx.x;
    for (int i = t; i < 2048; i += 1024) h[i] = 0;
    __syncthreads();
    const float4* pos4 = (const float4*)pos;
    const int base_q = blockIdx.x * 2048;    // quad index (4 particles each)
    float4 P[2][3];
    #pragma unroll
    for (int it = 0; it < 2; ++it) {
        const int q = base_q + (it << 10) + t;
        const float4 Pa = pos4[3 * q], Pb = pos4[3 * q + 1], Pc = pos4[3 * q + 2];
        P[it][0] = Pa; P[it][1] = Pb; P[it][2] = Pc;
        outp[3 * q]     = Pa;
        outp[3 * q + 1] = Pb;
        outp[3 * q + 2] = Pc;
        atomicAdd(&h[bucket_of(Pa.x, Pa.y)], 1u);
        atomicAdd(&h[bucket_of(Pa.w, Pb.x)], 1u);
        atomicAdd(&h[bucket_of(Pb.z, Pb.w)], 1u);
        atomicAdd(&h[bucket_of(Pc.y, Pc.z)], 1u);
    }
    __syncthreads();
    for (int i = t; i < 2048; i += 1024) {
        const u32 c = h[i];
        h[i] = c ? ((u32)i * BSTRIDE + atomicAdd(&gcnt[i], c)) : 0u;
    }
    __syncthreads();
    #pragma unroll
    for (int it = 0; it < 2; ++it) {
        const int q = base_q + (it << 10) + t;
        const int n = 4 * q;
        const float4 Pa = P[it][0], Pb = P[it][1], Pc = P[it][2];
        S[atomicAdd(&h[bucket_of(Pa.x, Pa.y)], 1u)] = make_rec(Pa.x, Pa.y, Pa.z, n);
        S[atomicAdd(&h[bucket_of(Pa.w, Pb.x)], 1u)] = make_rec(Pa.w, Pb.x, Pb.y, n + 1);
        S[atomicAdd(&h[bucket_of(Pb.z, Pb.w)], 1u)] = make_rec(Pb.z, Pb.w, Pc.x, n + 2);
        S[atomicAdd(&h[bucket_of(Pc.y, Pc.z)], 1u)] = make_rec(Pc.y, Pc.z, Pc.w, n + 3);
    }
}

__device__ __forceinline__ void decode(u64 v, int& iz, int& lx, int& ly,
                                       float& fx, float& fy, float& fz, int& n) {
    iz = (int)(v & 127);
    lx = (int)((v >> 7) & 3);
    ly = (int)((v >> 9) & 3);
    const float inv = 1.0f / 1024.0f;
    fx = (float)((v >> 11) & 1023) * inv;
    fy = (float)((v >> 21) & 1023) * inv;
    fz = (float)((v >> 31) & 1023) * inv;
    n = (int)((v >> 41) & 0x1FFFFF);
}

// GATHER-based paint: bin particles by local cell (1 LDS atomic each), then
// each staging cell gathers from <=8 neighbor cell lists (LDS reads, no atomics).
__global__ __launch_bounds__(512) void paint_kernel(const u64* __restrict__ S,
                                                    const u32* __restrict__ gcnt,
                                                    float* __restrict__ ST) {
    __shared__ u32 cnt[1024];        // per local cell (bx[0..3], by[0..1], bz[0..127])
    __shared__ u32 rec[1024 * CAP];  // qx|qy<<10|qz<<20
    __shared__ u64 ovf[128];
    __shared__ u32 novf;
    const int t = threadIdx.x;
    for (int i = t; i < 1024; i += 512) cnt[i] = 0;
    if (t == 0) novf = 0;
    __syncthreads();
    const int b = blockIdx.x;
    const int start = b * BSTRIDE;
    const int end = start + (int)gcnt[b];
    for (int i = start + t; i < end; i += 512) {
        const u64 v = S[i];
        const int iz = (int)(v & 127);
        const int lx = (int)((v >> 7) & 3);
        const int ly = (int)((v >> 9) & 1);
        const int cell = (((lx << 1) | ly) << 7) | iz;
        const u32 r = (u32)((v >> 11) & 0x3FFFFFFFull);
        const u32 slot = atomicAdd(&cnt[cell], 1u);
        if (slot < CAP) rec[cell * CAP + slot] = r;
        else {
            const u32 o = atomicAdd(&novf, 1u);
            if (o < 128u) ovf[o] = ((u64)cell << 32) | r;
        }
    }
    __syncthreads();
    const u32 nv = novf > 128u ? 128u : novf;
    const float inv = 1.0f / 1024.0f;
    for (int i = t; i < 1920; i += 512) {
        const int hx = i / 384;
        const int hy = (i >> 7) % 3;
        const int z  = i & 127;
        float acc = 0.0f;
        #pragma unroll
        for (int sx = 0; sx < 2; ++sx) {
            const int bx = hx - 1 + sx;            // sx=0 -> dx=1 (weight fx)
            if ((unsigned)bx > 3u) continue;
            #pragma unroll
            for (int sy = 0; sy < 2; ++sy) {
                const int by = hy - 1 + sy;
                if ((unsigned)by > 1u) continue;
                #pragma unroll
                for (int sz = 0; sz < 2; ++sz) {
                    const int bz = (z - 1 + sz) & 127;
                    const int c = (((bx << 1) | by) << 7) | bz;
                    const int m = (int)min(cnt[c], (u32)CAP);
                    const int rb = c * CAP;
                    for (int k = 0; k < m; ++k) {
                        const u32 r = rec[rb + k];
                        const float fx = (float)(r & 1023) * inv;
                        const float fy = (float)((r >> 10) & 1023) * inv;
                        const float fz = (float)(r >> 20) * inv;
                        const float wx = sx ? (1.0f - fx) : fx;
                        const float wy = sy ? (1.0f - fy) : fy;
                        const float wz = sz ? (1.0f - fz) : fz;
                        acc += wx * wy * wz;
                    }
                }
            }
        }
        for (u32 j = 0; j < nv; ++j) {
            const u64 o = ovf[j];
            const int c = (int)(o >> 32);
            const int obx = (c >> 8) & 3, oby = (c >> 7) & 1, obz = c & 127;
            const int dx = hx - obx, dy = hy - oby, dz = (z - obz) & 127;
            if ((unsigned)dx < 2u && (unsigned)dy < 2u && dz < 2) {
                const u32 r = (u32)o;
                const float fx = (float)(r & 1023) * inv;
                const float fy = (float)((r >> 10) & 1023) * inv;
                const float fz = (float)(r >> 20) * inv;
                acc += (dx ? fx : 1.0f - fx) * (dy ? fy : 1.0f - fy)
                     * (dz ? fz : 1.0f - fz);
            }
        }
        ST[(size_t)b * 1920 + i] = acc;
    }
}

// Sorted force readout: LDS-staged field tiles, one scattered 8B store per
// particle (packed bf16 gx|gy|gz).
__global__ __launch_bounds__(512) void force_kernel(const u64* __restrict__ S,
                                                    const u32* __restrict__ gcnt,
                                                    const u32* __restrict__ Abf,
                                                    const u16* __restrict__ Brl,
                                                    u64* __restrict__ VP) {
    __shared__ float2 sxy[1920];
    __shared__ float  szz[1920];
    const int t = threadIdx.x;
    const int b = blockIdx.x;
    const int x0 = (b >> 6) << 2, y0 = (b & 63) << 1;
    for (int i = t; i < 1920; i += 512) {
        const int hx = i / 384;
        const int hy = (i >> 7) % 3;
        const int z = i & 127;
        const int g = (((x0 + hx) & 127) << 14) | (((y0 + hy) & 127) << 7) | z;
        const u32 ab = Abf[g];
        sxy[i] = make_float2(__uint_as_float(ab << 16),
                             __uint_as_float(ab & 0xFFFF0000u));
        szz[i] = bf2f(Brl[g]);
    }
    __syncthreads();
    const int start = b * BSTRIDE;
    const int end = start + (int)gcnt[b];
    for (int i = start + t; i < end; i += 512) {
        int iz, lx, ly, n;
        float fx, fy, fz;
        decode(S[i], iz, lx, ly, fx, fy, fz, n);
        const float wx[2] = {1.0f - fx, fx};
        const float wy[2] = {1.0f - fy, fy};
        const float wz[2] = {1.0f - fz, fz};
        float gx = 0.f, gy = 0.f, gz = 0.f;
        #pragma unroll
        for (int dx = 0; dx < 2; ++dx)
            #pragma unroll
            for (int dy = 0; dy < 2; ++dy) {
                const int bi = ((lx + dx) * 3 + (ly + dy)) << 7;
                const float wxy = wx[dx] * wy[dy];
                #pragma unroll
                for (int dz = 0; dz < 2; ++dz) {
                    const int idx2 = bi + ((iz + dz) & 127);
                    const float w = wxy * wz[dz];
                    const float2 a = sxy[idx2];
                    gx += w * a.x;
                    gy += w * a.y;
                    gz += w * szz[idx2];
                }
            }
        VP[n] = (u64)f2bf(gx) | ((u64)f2bf(gy) << 16) | ((u64)f2bf(gz) << 32);
    }
}

// Streaming finalize: out_vel = vel + VP*sc, all coalesced (pos copy in bin).
__global__ __launch_bounds__(256) void finalize_kernel(const float* __restrict__ vel,
                                                       const u64* __restrict__ VP,
                                                       const float* __restrict__ fdf,
                                                       float* __restrict__ out) {
    const int tid = blockIdx.x * 256 + threadIdx.x;   // 524288 threads, 4 particles each
    const float sc = 0.2f / fdf[0];
    const float4* vel4 = (const float4*)vel;
    float4* outv = (float4*)out + (3 * NPART / 4);
    const float4 Va = vel4[3 * tid], Vb = vel4[3 * tid + 1], Vc = vel4[3 * tid + 2];
    const ulonglong2* VP2 = (const ulonglong2*)VP;
    const ulonglong2 qa = VP2[2 * tid];
    const ulonglong2 qb = VP2[2 * tid + 1];
    const u64 q[4] = {qa.x, qa.y, qb.x, qb.y};
    const float vv[12] = {Va.x, Va.y, Va.z, Va.w, Vb.x, Vb.y, Vb.z, Vb.w,
                          Vc.x, Vc.y, Vc.z, Vc.w};
    float ov[12];
    #pragma unroll
    for (int k = 0; k < 4; ++k) {
        const float gx = bf2f((u16)(q[k] & 0xFFFF));
        const float gy = bf2f((u16)((q[k] >> 16) & 0xFFFF));
        const float gz = bf2f((u16)((q[k] >> 32) & 0xFFFF));
        ov[3 * k]     = vv[3 * k]     + gx * sc;
        ov[3 * k + 1] = vv[3 * k + 1] + gy * sc;
        ov[3 * k + 2] = vv[3 * k + 2] + gz * sc;
    }
    outv[3 * tid]     = make_float4(ov[0], ov[1], ov[2], ov[3]);
    outv[3 * tid + 1] = make_float4(ov[4], ov[5], ov[6], ov[7]);
    outv[3 * tid + 2] = make_float4(ov[8], ov[9], ov[10], ov[11]);
}

extern "C" void kernel_launch(void* const* d_in, const int* in_sizes, int n_in,
                              void* d_out, int out_size, void* d_ws, size_t ws_size,
                              hipStream_t stream) {
    const float* pos = (const float*)d_in[0];
    const float* vel = (const float*)d_in[1];
    const float* fdf = (const float*)d_in[2];
    float* out = (float*)d_out;

    // ws layout (16 MiB = 1<<24 per slot):
    //   [0] A grid   [1] B grid   [2] ST staging   [3] Abf + Brl
    //   [4] VP packed forces      [5..6] S bucket regions (25.2 MB)  [7] counters
    char* w = (char*)d_ws;
    float2* A   = (float2*)(w);
    float2* B   = (float2*)(w + ((size_t)1 << 24));
    float*  ST  = (float*)(w + ((size_t)2 << 24));
    u32*    Abf = (u32*)(w + ((size_t)3 << 24));
    u16*    Brl = (u16*)(w + ((size_t)3 << 24) + (size_t)MESH3 * 4);
    u64*    VP  = (u64*)(w + ((size_t)4 << 24));
    u64*    S   = (u64*)(w + ((size_t)5 << 24));   // 2048*1536*8 = 25.2 MB (2 slots)
    u32*    gcnt = (u32*)(w + ((size_t)7 << 24));

    hipMemsetAsync(gcnt, 0, 2048 * sizeof(u32), stream);
    bin_kernel<<<256, 1024, 0, stream>>>(pos, gcnt, S, (float4*)out);

    paint_kernel<<<2048, 512, 0, stream>>>(S, gcnt, ST);

    fft_zy_fwd_mega<<<128, 1024, 0, stream>>>(ST, A);   // halo merge + fwd z + fwd y
    fft_x_mega<<<1024, 512, 0, stream>>>(A, B);         // fwd x + filter + inv x (A,B)
    fft_yz_inv_mega<<<256, 1024, 0, stream>>>(A, B, Abf, Brl);  // inv y + inv z + pack

    force_kernel<<<2048, 512, 0, stream>>>(S, gcnt, Abf, Brl, VP);
    finalize_kernel<<<2048, 256, 0, stream>>>(vel, VP, fdf, out);
}

// Round 10
// 249.442 us; speedup vs baseline: 1.0465x; 1.0465x over previous
//
#include <hip/hip_runtime.h>

#define MESH  128
#define MESH2 16384
#define MESH3 2097152
#define NPART MESH3
#define TILE  16
#define LDP   (TILE + 1)
#define LDP2  129     // full-plane pad: row stride 129 float2
#define CAP   6
#define BSTRIDE 1536   // slots per bucket region (mean 1024, >15 sigma headroom)
typedef unsigned int u32;
typedef unsigned short u16;
typedef unsigned long long u64;

__device__ __forceinline__ float2 cmul(float2 a, float2 b) {
    return make_float2(a.x * b.x - a.y * b.y, a.x * b.y + a.y * b.x);
}
__device__ __forceinline__ float2 cadd(float2 a, float2 b) {
    return make_float2(a.x + b.x, a.y + b.y);
}
__device__ __forceinline__ float2 csub(float2 a, float2 b) {
    return make_float2(a.x - b.x, a.y - b.y);
}
__device__ __forceinline__ u16 f2bf(float x) {
    u32 b = __float_as_uint(x);
    return (u16)((b + 0x7FFFu + ((b >> 16) & 1u)) >> 16);   // RNE
}
__device__ __forceinline__ float bf2f(u16 h) {
    return __uint_as_float(((u32)h) << 16);
}

// ---------------- radix-4 128-point FFT cores (in LDS, butterfly on dim 0) ---
// 512-thread version: l = t&15 (lane within tile), bb = t>>4 in [0,32).
__device__ __forceinline__ void fft128_fwd_lds(float2 (*__restrict__ s)[LDP],
                                               const float2* __restrict__ tw,
                                               int l, int bb) {
    #pragma unroll
    for (int pr = 0; pr < 3; ++pr) {
        const int st = 2 * pr;
        const int logq = 5 - st;
        const int q = 1 << logq;
        const int j = bb & (q - 1);
        const int g = bb >> logq;
        const int i0 = (g << (logq + 2)) + j;
        const float2 x0 = s[i0][l], x1 = s[i0 + q][l];
        const float2 x2 = s[i0 + 2 * q][l], x3 = s[i0 + 3 * q][l];
        const int m = j << st;
        const float2 wA = tw[m], wA2 = tw[m + 32], wB = tw[2 * m];
        const float2 u0 = cadd(x0, x2), u2 = cmul(csub(x0, x2), wA);
        const float2 u1 = cadd(x1, x3), u3 = cmul(csub(x1, x3), wA2);
        s[i0][l]         = cadd(u0, u1);
        s[i0 + q][l]     = cmul(csub(u0, u1), wB);
        s[i0 + 2 * q][l] = cadd(u2, u3);
        s[i0 + 3 * q][l] = cmul(csub(u2, u3), wB);
        __syncthreads();
    }
    #pragma unroll
    for (int itn = 0; itn < 2; ++itn) {
        const int i0 = (bb + (itn << 5)) << 1;
        const float2 x0 = s[i0][l], x1 = s[i0 + 1][l];
        s[i0][l]     = cadd(x0, x1);
        s[i0 + 1][l] = csub(x0, x1);
    }
}

// Dual-array DIT inverse (interleaved for ILP) — used by fft_x_mega.
__device__ __forceinline__ void fft128_inv_lds_dual(float2 (*__restrict__ SA)[LDP],
                                                    float2 (*__restrict__ SB)[LDP],
                                                    const float2* __restrict__ tw,
                                                    int l, int bb) {
    #pragma unroll
    for (int pr = 0; pr < 3; ++pr) {
        const int st = 2 * pr;
        const int p = 1 << st;
        const int j = bb & (p - 1);
        const int g = bb >> st;
        const int i0 = (g << (st + 2)) + j;
        const float2 wA = tw[j << (6 - st)];
        const int mB = j << (5 - st);
        const float2 wB = tw[mB], wB2 = tw[mB + 32];
        {
            const float2 x0 = SA[i0][l], x1 = SA[i0 + p][l];
            const float2 x2 = SA[i0 + 2 * p][l], x3 = SA[i0 + 3 * p][l];
            const float2 a1 = cmul(x1, wA), a3 = cmul(x3, wA);
            const float2 u0 = cadd(x0, a1), u1 = csub(x0, a1);
            const float2 u2 = cadd(x2, a3), u3 = csub(x2, a3);
            const float2 b2 = cmul(u2, wB), b3 = cmul(u3, wB2);
            SA[i0][l]         = cadd(u0, b2);
            SA[i0 + p][l]     = cadd(u1, b3);
            SA[i0 + 2 * p][l] = csub(u0, b2);
            SA[i0 + 3 * p][l] = csub(u1, b3);
        }
        {
            const float2 x0 = SB[i0][l], x1 = SB[i0 + p][l];
            const float2 x2 = SB[i0 + 2 * p][l], x3 = SB[i0 + 3 * p][l];
            const float2 a1 = cmul(x1, wA), a3 = cmul(x3, wA);
            const float2 u0 = cadd(x0, a1), u1 = csub(x0, a1);
            const float2 u2 = cadd(x2, a3), u3 = csub(x2, a3);
            const float2 b2 = cmul(u2, wB), b3 = cmul(u3, wB2);
            SB[i0][l]         = cadd(u0, b2);
            SB[i0 + p][l]     = cadd(u1, b3);
            SB[i0 + 2 * p][l] = csub(u0, b2);
            SB[i0 + 3 * p][l] = csub(u1, b3);
        }
        __syncthreads();
    }
    #pragma unroll
    for (int itn = 0; itn < 2; ++itn) {
        const int b = bb + (itn << 5);
        const float2 w = tw[b];
        {
            const float2 u = SA[b][l];
            const float2 v = cmul(SA[b + 64][l], w);
            SA[b][l]      = cadd(u, v);
            SA[b + 64][l] = csub(u, v);
        }
        {
            const float2 u = SB[b][l];
            const float2 v = cmul(SB[b + 64][l], w);
            SB[b][l]      = cadd(u, v);
            SB[b + 64][l] = csub(u, v);
        }
    }
}

// ---------------- y-axis forward pass ----------------------------------------
__global__ __launch_bounds__(512) void fft_y_fwd(float2* __restrict__ data) {
    __shared__ float2 s[MESH][LDP];
    __shared__ float2 tw[64];
    const int t = threadIdx.x;
    if (t < 64) {
        float sv, cv;
        sincospif(-(float)t / 64.0f, &sv, &cv);
        tw[t] = make_float2(cv, sv);
    }
    const int outer = blockIdx.x >> 3;
    const int z0 = (blockIdx.x & 7) * TILE;
    const int base = outer * MESH2 + z0;
    for (int i = t; i < MESH * TILE; i += 512) {
        const int l = i & 15, e = i >> 4;
        s[e][l] = data[base + e * MESH + l];
    }
    __syncthreads();
    const int l  = t & 15;
    const int bb = t >> 4;
    fft128_fwd_lds(s, tw, l, bb);
    __syncthreads();
    for (int i = t; i < MESH * TILE; i += 512) {
        const int l2 = i & 15, e = i >> 4;
        data[base + e * MESH + l2] = s[e][l2];
    }
}

// ------- z-forward FFT fused with the staging-tile halo merge (paint flush) --
// ST: 2048 tiles x 1920 floats, tile layout [hx:5][hy:3][z:128].
__global__ __launch_bounds__(512) void fft_z_fwd_merge(const float* __restrict__ ST,
                                                       float2* __restrict__ out) {
    __shared__ float2 s[MESH][LDP];
    __shared__ float2 tw[64];
    const int t = threadIdx.x;
    if (t < 64) {
        float sv, cv;
        sincospif(-(float)t / 64.0f, &sv, &cv);
        tw[t] = make_float2(cv, sv);
    }
    const int col0 = blockIdx.x * TILE;
    const int base = col0 * MESH;
    for (int i = t; i < MESH * TILE; i += 512) {
        const int lc = i >> 7;
        const int z  = i & 127;
        const int c  = col0 + lc;
        const int x = c >> 7, y = c & 127;
        const int tx = x >> 2, ty = y >> 1;
        const int hx = x & 3,  hy = y & 1;
        float v = ST[((tx << 6) | ty) * 1920 + ((hx * 3 + hy) << 7) + z];
        const int txm = (tx + 31) & 31;
        const int tym = (ty + 63) & 63;
        if (hx == 0)
            v += ST[((txm << 6) | ty) * 1920 + ((12 + hy) << 7) + z];
        if (hy == 0) {
            v += ST[((tx << 6) | tym) * 1920 + ((hx * 3 + 2) << 7) + z];
            if (hx == 0)
                v += ST[((txm << 6) | tym) * 1920 + (14 << 7) + z];
        }
        s[z][lc] = make_float2(v, 0.0f);
    }
    __syncthreads();
    const int l  = t & 15;
    const int bb = t >> 4;
    fft128_fwd_lds(s, tw, l, bb);
    __syncthreads();
    for (int i = t; i < MESH * TILE; i += 512)
        out[base + i] = s[i & 127][i >> 7];
}

// ------- fused inverse y + inverse z + bf16 pack, full (y,z) plane in LDS ----
// 256 blocks: [0,128) = A plane x -> Abf bf16x2, [128,256) = B plane x -> Brl.
__global__ __launch_bounds__(1024) void fft_yz_inv_mega(const float2* __restrict__ A,
                                                        const float2* __restrict__ B,
                                                        u32* __restrict__ Abf,
                                                        u16* __restrict__ Brl) {
    __shared__ float2 s[MESH][LDP2];
    __shared__ float2 tw[64];
    const int t = threadIdx.x;
    if (t < 64) {
        float sv, cv;
        sincospif(-(float)t / 64.0f, &sv, &cv);
        tw[t] = make_float2(cv, -sv);     // e^{+i pi m/64}
    }
    const bool isB = blockIdx.x >= 128;
    const int x = blockIdx.x & 127;
    const float2* __restrict__ in = isB ? B : A;
    const int gbase = x * MESH2;
    for (int i = t; i < MESH * MESH; i += 1024)
        s[i >> 7][i & 127] = in[gbase + i];      // s[y][z]
    __syncthreads();

    const int col = t & 127;          // phase-1: z column
    const int wrk = t >> 7;           // [0,8)

    // ---- phase 1: inverse DIT along y (first index) ----
    #pragma unroll
    for (int pr = 0; pr < 3; ++pr) {
        const int st = 2 * pr;
        const int p = 1 << st;
        #pragma unroll
        for (int n = 0; n < 4; ++n) {
            const int bb = wrk | (n << 3);               // [0,32)
            const int j = bb & (p - 1);
            const int g = bb >> st;
            const int i0 = (g << (st + 2)) + j;
            const float2 wA = tw[j << (6 - st)];
            const int mB = j << (5 - st);
            const float2 wB = tw[mB], wB2 = tw[mB + 32];
            const float2 x0 = s[i0][col], x1 = s[i0 + p][col];
            const float2 x2 = s[i0 + 2 * p][col], x3 = s[i0 + 3 * p][col];
            const float2 a1 = cmul(x1, wA), a3 = cmul(x3, wA);
            const float2 u0 = cadd(x0, a1), u1 = csub(x0, a1);
            const float2 u2 = cadd(x2, a3), u3 = csub(x2, a3);
            const float2 b2 = cmul(u2, wB), b3 = cmul(u3, wB2);
            s[i0][col]         = cadd(u0, b2);
            s[i0 + p][col]     = cadd(u1, b3);
            s[i0 + 2 * p][col] = csub(u0, b2);
            s[i0 + 3 * p][col] = csub(u1, b3);
        }
        __syncthreads();
    }
    #pragma unroll
    for (int n = 0; n < 8; ++n) {
        const int b = wrk | (n << 3);                    // [0,64)
        const float2 w = tw[b];
        const float2 u = s[b][col];
        const float2 v = cmul(s[b + 64][col], w);
        s[b][col]      = cadd(u, v);
        s[b + 64][col] = csub(u, v);
    }
    __syncthreads();

    // ---- phase 2: inverse DIT along z (second index) ----
    const int row = t & 127;          // phase-2: y row
    #pragma unroll
    for (int pr = 0; pr < 3; ++pr) {
        const int st = 2 * pr;
        const int p = 1 << st;
        #pragma unroll
        for (int n = 0; n < 4; ++n) {
            const int bb = wrk | (n << 3);
            const int j = bb & (p - 1);
            const int g = bb >> st;
            const int i0 = (g << (st + 2)) + j;
            const float2 wA = tw[j << (6 - st)];
            const int mB = j << (5 - st);
            const float2 wB = tw[mB], wB2 = tw[mB + 32];
            const float2 x0 = s[row][i0], x1 = s[row][i0 + p];
            const float2 x2 = s[row][i0 + 2 * p], x3 = s[row][i0 + 3 * p];
            const float2 a1 = cmul(x1, wA), a3 = cmul(x3, wA);
            const float2 u0 = cadd(x0, a1), u1 = csub(x0, a1);
            const float2 u2 = cadd(x2, a3), u3 = csub(x2, a3);
            const float2 b2 = cmul(u2, wB), b3 = cmul(u3, wB2);
            s[row][i0]         = cadd(u0, b2);
            s[row][i0 + p]     = cadd(u1, b3);
            s[row][i0 + 2 * p] = csub(u0, b2);
            s[row][i0 + 3 * p] = csub(u1, b3);
        }
        __syncthreads();
    }
    #pragma unroll
    for (int n = 0; n < 8; ++n) {
        const int b = wrk | (n << 3);
        const float2 w = tw[b];
        const float2 u = s[row][b];
        const float2 v = cmul(s[row][b + 64], w);
        s[row][b]      = cadd(u, v);
        s[row][b + 64] = csub(u, v);
    }
    __syncthreads();

    if (isB) {
        for (int i = t; i < MESH * MESH; i += 1024)
            Brl[gbase + i] = f2bf(s[i >> 7][i & 127].x);
    } else {
        for (int i = t; i < MESH * MESH; i += 1024) {
            const float2 v = s[i >> 7][i & 127];
            Abf[gbase + i] = (u32)f2bf(v.x) | ((u32)f2bf(v.y) << 16);
        }
    }
}

// Fused: forward x-FFT (DIF) -> filter -> inverse x-FFT (DIT) on A and B lines.
__global__ __launch_bounds__(512) void fft_x_mega(float2* __restrict__ A,
                                                  float2* __restrict__ B) {
    __shared__ float2 SA[MESH][LDP];
    __shared__ float2 SB[MESH][LDP];
    __shared__ float2 twf[64];
    __shared__ float2 twi[64];
    const int t = threadIdx.x;
    if (t < 64) {
        float sv, cv;
        sincospif(-(float)t / 64.0f, &sv, &cv);
        twf[t] = make_float2(cv, sv);
        twi[t] = make_float2(cv, -sv);
    }
    const int cy = blockIdx.x >> 3;
    const int z0 = (blockIdx.x & 7) * TILE;
    const int base = cy * MESH + z0;

    for (int i = t; i < MESH * TILE; i += 512) {
        const int l = i & 15, e = i >> 4;
        SA[e][l] = A[base + e * MESH2 + l];
    }
    __syncthreads();

    const int l  = t & 15;
    const int bb = t >> 4;
    fft128_fwd_lds(SA, twf, l, bb);
    __syncthreads();

    const int jy = (int)(__brev((unsigned)cy) >> 25);
    const float c = 6.28318530717958647692f / 128.0f;
    const float ky = c * (float)(jy < 64 ? jy : jy - 128);
    for (int i = t; i < MESH * TILE; i += 512) {
        const int e = i & 127, ll = i >> 7;
        const int jx = (int)(__brev((unsigned)e) >> 25);
        const int jz = (int)(__brev((unsigned)(z0 + ll)) >> 25);
        const float kx = c * (float)(jx < 64 ? jx : jx - 128);
        const float kz = c * (float)(jz < 64 ? jz : jz - 128);
        const float kk = kx * kx + ky * ky + kz * kz;
        float2 a = SA[e][ll];
        float2 av = make_float2(0.f, 0.f), bv = make_float2(0.f, 0.f);
        if (kk > 0.0f) {
            const float inv_kk = 1.0f / kk;
            const float rng = __expf(-0.09f * inv_kk - kk * kk);  // KL^2=0.09, KS^4=1
            const float sc  = -inv_kk * rng * (1.0f / 2097152.0f);
            const float pr = a.x * sc, pi = a.y * sc;
            av = make_float2(ky * pr + kx * pi, ky * pi - kx * pr);
            bv = make_float2(kz * pi, -kz * pr);
        }
        SA[e][ll] = av;
        SB[e][ll] = bv;
    }
    __syncthreads();

    fft128_inv_lds_dual(SA, SB, twi, l, bb);
    __syncthreads();

    for (int i = t; i < MESH * TILE; i += 512) {
        const int l2 = i & 15, e = i >> 4;
        A[base + e * MESH2 + l2] = SA[e][l2];
        B[base + e * MESH2 + l2] = SB[e][l2];
    }
}

// ---------------- particle binning: 2048 buckets (4x2 columns) ----------------

__device__ __forceinline__ int bucket_of(float px, float py) {
    const int ix = ((int)floorf(px)) & 127;
    const int iy = ((int)floorf(py)) & 127;
    return ((ix >> 2) << 6) | (iy >> 1);
}

__device__ __forceinline__ u64 make_rec(float px, float py, float pz, int n) {
    const float fxx = floorf(px), fyy = floorf(py), fzz = floorf(pz);
    const int ix = ((int)fxx) & 127, iy = ((int)fyy) & 127, iz = ((int)fzz) & 127;
    const u32 qx = (u32)((px - fxx) * 1024.0f);
    const u32 qy = (u32)((py - fyy) * 1024.0f);
    const u32 qz = (u32)((pz - fzz) * 1024.0f);
    return (u64)iz | ((u64)(ix & 3) << 7) | ((u64)(iy & 1) << 9)
         | ((u64)qx << 11) | ((u64)qy << 21) | ((u64)qz << 31)
         | ((u64)(u32)n << 41);
}

// Fused hist+scan+scatter: one pass. Each bucket owns a fixed BSTRIDE region
// of S; a block reserves its span with one global atomicAdd per non-empty
// bucket. Also streams the pos copy to out.
__global__ __launch_bounds__(1024) void bin_kernel(const float* __restrict__ pos,
                                                   u32* __restrict__ gcnt,
                                                   u64* __restrict__ S,
                                                   float4* __restrict__ outp) {
    __shared__ u32 h[2048];
    const int t = threadIdx.x;
    for (int i = t; i < 2048; i += 1024) h[i] = 0;
    __syncthreads();
    const float4* pos4 = (const float4*)pos;
    const int base_q = blockIdx.x * 2048;    // quad index (4 particles each)
    float4 P[2][3];
    #pragma unroll
    for (int it = 0; it < 2; ++it) {
        const int q = base_q + (it << 10) + t;
        const float4 Pa = pos4[3 * q], Pb = pos4[3 * q + 1], Pc = pos4[3 * q + 2];
        P[it][0] = Pa; P[it][1] = Pb; P[it][2] = Pc;
        outp[3 * q]     = Pa;
        outp[3 * q + 1] = Pb;
        outp[3 * q + 2] = Pc;
        atomicAdd(&h[bucket_of(Pa.x, Pa.y)], 1u);
        atomicAdd(&h[bucket_of(Pa.w, Pb.x)], 1u);
        atomicAdd(&h[bucket_of(Pb.z, Pb.w)], 1u);
        atomicAdd(&h[bucket_of(Pc.y, Pc.z)], 1u);
    }
    __syncthreads();
    for (int i = t; i < 2048; i += 1024) {
        const u32 c = h[i];
        h[i] = c ? ((u32)i * BSTRIDE + atomicAdd(&gcnt[i], c)) : 0u;
    }
    __syncthreads();
    #pragma unroll
    for (int it = 0; it < 2; ++it) {
        const int q = base_q + (it << 10) + t;
        const int n = 4 * q;
        const float4 Pa = P[it][0], Pb = P[it][1], Pc = P[it][2];
        S[atomicAdd(&h[bucket_of(Pa.x, Pa.y)], 1u)] = make_rec(Pa.x, Pa.y, Pa.z, n);
        S[atomicAdd(&h[bucket_of(Pa.w, Pb.x)], 1u)] = make_rec(Pa.w, Pb.x, Pb.y, n + 1);
        S[atomicAdd(&h[bucket_of(Pb.z, Pb.w)], 1u)] = make_rec(Pb.z, Pb.w, Pc.x, n + 2);
        S[atomicAdd(&h[bucket_of(Pc.y, Pc.z)], 1u)] = make_rec(Pc.y, Pc.z, Pc.w, n + 3);
    }
}

__device__ __forceinline__ void decode(u64 v, int& iz, int& lx, int& ly,
                                       float& fx, float& fy, float& fz, int& n) {
    iz = (int)(v & 127);
    lx = (int)((v >> 7) & 3);
    ly = (int)((v >> 9) & 3);
    const float inv = 1.0f / 1024.0f;
    fx = (float)((v >> 11) & 1023) * inv;
    fy = (float)((v >> 21) & 1023) * inv;
    fz = (float)((v >> 31) & 1023) * inv;
    n = (int)((v >> 41) & 0x1FFFFF);
}

// GATHER-based paint: bin particles by local cell (1 LDS atomic each), then
// each staging cell gathers from <=8 neighbor cell lists (LDS reads, no atomics).
// XCD-aware bucket swizzle: each XCD gets a contiguous chunk of 256 buckets.
__global__ __launch_bounds__(512) void paint_kernel(const u64* __restrict__ S,
                                                    const u32* __restrict__ gcnt,
                                                    float* __restrict__ ST) {
    __shared__ u32 cnt[1024];        // per local cell (bx[0..3], by[0..1], bz[0..127])
    __shared__ u32 rec[1024 * CAP];  // qx|qy<<10|qz<<20
    __shared__ u64 ovf[128];
    __shared__ u32 novf;
    const int t = threadIdx.x;
    for (int i = t; i < 1024; i += 512) cnt[i] = 0;
    if (t == 0) novf = 0;
    __syncthreads();
    const int b = ((blockIdx.x & 7) << 8) | (blockIdx.x >> 3);   // bijective (2048%8==0)
    const int start = b * BSTRIDE;
    const int end = start + (int)gcnt[b];
    for (int i = start + t; i < end; i += 512) {
        const u64 v = S[i];
        const int iz = (int)(v & 127);
        const int lx = (int)((v >> 7) & 3);
        const int ly = (int)((v >> 9) & 1);
        const int cell = (((lx << 1) | ly) << 7) | iz;
        const u32 r = (u32)((v >> 11) & 0x3FFFFFFFull);
        const u32 slot = atomicAdd(&cnt[cell], 1u);
        if (slot < CAP) rec[cell * CAP + slot] = r;
        else {
            const u32 o = atomicAdd(&novf, 1u);
            if (o < 128u) ovf[o] = ((u64)cell << 32) | r;
        }
    }
    __syncthreads();
    const u32 nv = novf > 128u ? 128u : novf;
    const float inv = 1.0f / 1024.0f;
    for (int i = t; i < 1920; i += 512) {
        const int hx = i / 384;
        const int hy = (i >> 7) % 3;
        const int z  = i & 127;
        float acc = 0.0f;
        #pragma unroll
        for (int sx = 0; sx < 2; ++sx) {
            const int bx = hx - 1 + sx;            // sx=0 -> dx=1 (weight fx)
            if ((unsigned)bx > 3u) continue;
            #pragma unroll
            for (int sy = 0; sy < 2; ++sy) {
                const int by = hy - 1 + sy;
                if ((unsigned)by > 1u) continue;
                #pragma unroll
                for (int sz = 0; sz < 2; ++sz) {
                    const int bz = (z - 1 + sz) & 127;
                    const int c = (((bx << 1) | by) << 7) | bz;
                    const int m = (int)min(cnt[c], (u32)CAP);
                    const int rb = c * CAP;
                    for (int k = 0; k < m; ++k) {
                        const u32 r = rec[rb + k];
                        const float fx = (float)(r & 1023) * inv;
                        const float fy = (float)((r >> 10) & 1023) * inv;
                        const float fz = (float)(r >> 20) * inv;
                        const float wx = sx ? (1.0f - fx) : fx;
                        const float wy = sy ? (1.0f - fy) : fy;
                        const float wz = sz ? (1.0f - fz) : fz;
                        acc += wx * wy * wz;
                    }
                }
            }
        }
        for (u32 j = 0; j < nv; ++j) {
            const u64 o = ovf[j];
            const int c = (int)(o >> 32);
            const int obx = (c >> 8) & 3, oby = (c >> 7) & 1, obz = c & 127;
            const int dx = hx - obx, dy = hy - oby, dz = (z - obz) & 127;
            if ((unsigned)dx < 2u && (unsigned)dy < 2u && dz < 2) {
                const u32 r = (u32)o;
                const float fx = (float)(r & 1023) * inv;
                const float fy = (float)((r >> 10) & 1023) * inv;
                const float fz = (float)(r >> 20) * inv;
                acc += (dx ? fx : 1.0f - fx) * (dy ? fy : 1.0f - fy)
                     * (dz ? fz : 1.0f - fz);
            }
        }
        ST[(size_t)b * 1920 + i] = acc;
    }
}

// Sorted force readout: LDS-staged field tiles, one scattered 8B store per
// particle (packed bf16 gx|gy|gz). XCD-aware bucket swizzle as in paint.
__global__ __launch_bounds__(512) void force_kernel(const u64* __restrict__ S,
                                                    const u32* __restrict__ gcnt,
                                                    const u32* __restrict__ Abf,
                                                    const u16* __restrict__ Brl,
                                                    u64* __restrict__ VP) {
    __shared__ float2 sxy[1920];
    __shared__ float  szz[1920];
    const int t = threadIdx.x;
    const int b = ((blockIdx.x & 7) << 8) | (blockIdx.x >> 3);   // bijective
    const int x0 = (b >> 6) << 2, y0 = (b & 63) << 1;
    for (int i = t; i < 1920; i += 512) {
        const int hx = i / 384;
        const int hy = (i >> 7) % 3;
        const int z = i & 127;
        const int g = (((x0 + hx) & 127) << 14) | (((y0 + hy) & 127) << 7) | z;
        const u32 ab = Abf[g];
        sxy[i] = make_float2(__uint_as_float(ab << 16),
                             __uint_as_float(ab & 0xFFFF0000u));
        szz[i] = bf2f(Brl[g]);
    }
    __syncthreads();
    const int start = b * BSTRIDE;
    const int end = start + (int)gcnt[b];
    for (int i = start + t; i < end; i += 512) {
        int iz, lx, ly, n;
        float fx, fy, fz;
        decode(S[i], iz, lx, ly, fx, fy, fz, n);
        const float wx[2] = {1.0f - fx, fx};
        const float wy[2] = {1.0f - fy, fy};
        const float wz[2] = {1.0f - fz, fz};
        float gx = 0.f, gy = 0.f, gz = 0.f;
        #pragma unroll
        for (int dx = 0; dx < 2; ++dx)
            #pragma unroll
            for (int dy = 0; dy < 2; ++dy) {
                const int bi = ((lx + dx) * 3 + (ly + dy)) << 7;
                const float wxy = wx[dx] * wy[dy];
                #pragma unroll
                for (int dz = 0; dz < 2; ++dz) {
                    const int idx2 = bi + ((iz + dz) & 127);
                    const float w = wxy * wz[dz];
                    const float2 a = sxy[idx2];
                    gx += w * a.x;
                    gy += w * a.y;
                    gz += w * szz[idx2];
                }
            }
        VP[n] = (u64)f2bf(gx) | ((u64)f2bf(gy) << 16) | ((u64)f2bf(gz) << 32);
    }
}

// Streaming finalize: out_vel = vel + VP*sc, all coalesced (pos copy in bin).
__global__ __launch_bounds__(256) void finalize_kernel(const float* __restrict__ vel,
                                                       const u64* __restrict__ VP,
                                                       const float* __restrict__ fdf,
                                                       float* __restrict__ out) {
    const int tid = blockIdx.x * 256 + threadIdx.x;   // 524288 threads, 4 particles each
    const float sc = 0.2f / fdf[0];
    const float4* vel4 = (const float4*)vel;
    float4* outv = (float4*)out + (3 * NPART / 4);
    const float4 Va = vel4[3 * tid], Vb = vel4[3 * tid + 1], Vc = vel4[3 * tid + 2];
    const ulonglong2* VP2 = (const ulonglong2*)VP;
    const ulonglong2 qa = VP2[2 * tid];
    const ulonglong2 qb = VP2[2 * tid + 1];
    const u64 q[4] = {qa.x, qa.y, qb.x, qb.y};
    const float vv[12] = {Va.x, Va.y, Va.z, Va.w, Vb.x, Vb.y, Vb.z, Vb.w,
                          Vc.x, Vc.y, Vc.z, Vc.w};
    float ov[12];
    #pragma unroll
    for (int k = 0; k < 4; ++k) {
        const float gx = bf2f((u16)(q[k] & 0xFFFF));
        const float gy = bf2f((u16)((q[k] >> 16) & 0xFFFF));
        const float gz = bf2f((u16)((q[k] >> 32) & 0xFFFF));
        ov[3 * k]     = vv[3 * k]     + gx * sc;
        ov[3 * k + 1] = vv[3 * k + 1] + gy * sc;
        ov[3 * k + 2] = vv[3 * k + 2] + gz * sc;
    }
    outv[3 * tid]     = make_float4(ov[0], ov[1], ov[2], ov[3]);
    outv[3 * tid + 1] = make_float4(ov[4], ov[5], ov[6], ov[7]);
    outv[3 * tid + 2] = make_float4(ov[8], ov[9], ov[10], ov[11]);
}

extern "C" void kernel_launch(void* const* d_in, const int* in_sizes, int n_in,
                              void* d_out, int out_size, void* d_ws, size_t ws_size,
                              hipStream_t stream) {
    const float* pos = (const float*)d_in[0];
    const float* vel = (const float*)d_in[1];
    const float* fdf = (const float*)d_in[2];
    float* out = (float*)d_out;

    // ws layout (16 MiB = 1<<24 per slot):
    //   [0] A grid   [1] B grid   [2] ST staging   [3] Abf + Brl
    //   [4] VP packed forces      [5..6] S bucket regions (25.2 MB)  [7] counters
    char* w = (char*)d_ws;
    float2* A   = (float2*)(w);
    float2* B   = (float2*)(w + ((size_t)1 << 24));
    float*  ST  = (float*)(w + ((size_t)2 << 24));
    u32*    Abf = (u32*)(w + ((size_t)3 << 24));
    u16*    Brl = (u16*)(w + ((size_t)3 << 24) + (size_t)MESH3 * 4);
    u64*    VP  = (u64*)(w + ((size_t)4 << 24));
    u64*    S   = (u64*)(w + ((size_t)5 << 24));   // 2048*1536*8 = 25.2 MB (2 slots)
    u32*    gcnt = (u32*)(w + ((size_t)7 << 24));

    hipMemsetAsync(gcnt, 0, 2048 * sizeof(u32), stream);
    bin_kernel<<<256, 1024, 0, stream>>>(pos, gcnt, S, (float4*)out);

    paint_kernel<<<2048, 512, 0, stream>>>(S, gcnt, ST);

    fft_z_fwd_merge<<<1024, 512, 0, stream>>>(ST, A);   // halo merge + fwd z
    fft_y_fwd<<<1024, 512, 0, stream>>>(A);
    fft_x_mega<<<1024, 512, 0, stream>>>(A, B);         // fwd x + filter + inv x (A,B)
    fft_yz_inv_mega<<<256, 1024, 0, stream>>>(A, B, Abf, Brl);  // inv y + inv z + pack

    force_kernel<<<2048, 512, 0, stream>>>(S, gcnt, Abf, Brl, VP);
    finalize_kernel<<<2048, 256, 0, stream>>>(vel, VP, fdf, out);
}

// Round 12
// 247.171 us; speedup vs baseline: 1.0562x; 1.0092x over previous
//
#include <hip/hip_runtime.h>

#define MESH  128
#define MESH2 16384
#define MESH3 2097152
#define NPART MESH3
#define TILE  16
#define LDP   (TILE + 1)
#define LDP2  129     // full-plane pad: row stride 129 float2
#define CAP   6
#define BSTRIDE 1536   // slots per bucket region (mean 1024, >15 sigma headroom)
typedef unsigned int u32;
typedef unsigned short u16;
typedef unsigned long long u64;

__device__ __forceinline__ float2 cmul(float2 a, float2 b) {
    return make_float2(a.x * b.x - a.y * b.y, a.x * b.y + a.y * b.x);
}
__device__ __forceinline__ float2 cadd(float2 a, float2 b) {
    return make_float2(a.x + b.x, a.y + b.y);
}
__device__ __forceinline__ float2 csub(float2 a, float2 b) {
    return make_float2(a.x - b.x, a.y - b.y);
}
__device__ __forceinline__ u16 f2bf(float x) {
    u32 b = __float_as_uint(x);
    return (u16)((b + 0x7FFFu + ((b >> 16) & 1u)) >> 16);   // RNE
}
__device__ __forceinline__ float bf2f(u16 h) {
    return __uint_as_float(((u32)h) << 16);
}

// ---------------- radix-4 128-point FFT cores (in LDS, butterfly on dim 0) ---
// 512-thread version: l = t&15 (lane within tile), bb = t>>4 in [0,32).
__device__ __forceinline__ void fft128_fwd_lds(float2 (*__restrict__ s)[LDP],
                                               const float2* __restrict__ tw,
                                               int l, int bb) {
    #pragma unroll
    for (int pr = 0; pr < 3; ++pr) {
        const int st = 2 * pr;
        const int logq = 5 - st;
        const int q = 1 << logq;
        const int j = bb & (q - 1);
        const int g = bb >> logq;
        const int i0 = (g << (logq + 2)) + j;
        const float2 x0 = s[i0][l], x1 = s[i0 + q][l];
        const float2 x2 = s[i0 + 2 * q][l], x3 = s[i0 + 3 * q][l];
        const int m = j << st;
        const float2 wA = tw[m], wA2 = tw[m + 32], wB = tw[2 * m];
        const float2 u0 = cadd(x0, x2), u2 = cmul(csub(x0, x2), wA);
        const float2 u1 = cadd(x1, x3), u3 = cmul(csub(x1, x3), wA2);
        s[i0][l]         = cadd(u0, u1);
        s[i0 + q][l]     = cmul(csub(u0, u1), wB);
        s[i0 + 2 * q][l] = cadd(u2, u3);
        s[i0 + 3 * q][l] = cmul(csub(u2, u3), wB);
        __syncthreads();
    }
    #pragma unroll
    for (int itn = 0; itn < 2; ++itn) {
        const int i0 = (bb + (itn << 5)) << 1;
        const float2 x0 = s[i0][l], x1 = s[i0 + 1][l];
        s[i0][l]     = cadd(x0, x1);
        s[i0 + 1][l] = csub(x0, x1);
    }
}

// Dual-array DIT inverse (interleaved for ILP) — used by fft_x_mega.
__device__ __forceinline__ void fft128_inv_lds_dual(float2 (*__restrict__ SA)[LDP],
                                                    float2 (*__restrict__ SB)[LDP],
                                                    const float2* __restrict__ tw,
                                                    int l, int bb) {
    #pragma unroll
    for (int pr = 0; pr < 3; ++pr) {
        const int st = 2 * pr;
        const int p = 1 << st;
        const int j = bb & (p - 1);
        const int g = bb >> st;
        const int i0 = (g << (st + 2)) + j;
        const float2 wA = tw[j << (6 - st)];
        const int mB = j << (5 - st);
        const float2 wB = tw[mB], wB2 = tw[mB + 32];
        {
            const float2 x0 = SA[i0][l], x1 = SA[i0 + p][l];
            const float2 x2 = SA[i0 + 2 * p][l], x3 = SA[i0 + 3 * p][l];
            const float2 a1 = cmul(x1, wA), a3 = cmul(x3, wA);
            const float2 u0 = cadd(x0, a1), u1 = csub(x0, a1);
            const float2 u2 = cadd(x2, a3), u3 = csub(x2, a3);
            const float2 b2 = cmul(u2, wB), b3 = cmul(u3, wB2);
            SA[i0][l]         = cadd(u0, b2);
            SA[i0 + p][l]     = cadd(u1, b3);
            SA[i0 + 2 * p][l] = csub(u0, b2);
            SA[i0 + 3 * p][l] = csub(u1, b3);
        }
        {
            const float2 x0 = SB[i0][l], x1 = SB[i0 + p][l];
            const float2 x2 = SB[i0 + 2 * p][l], x3 = SB[i0 + 3 * p][l];
            const float2 a1 = cmul(x1, wA), a3 = cmul(x3, wA);
            const float2 u0 = cadd(x0, a1), u1 = csub(x0, a1);
            const float2 u2 = cadd(x2, a3), u3 = csub(x2, a3);
            const float2 b2 = cmul(u2, wB), b3 = cmul(u3, wB2);
            SB[i0][l]         = cadd(u0, b2);
            SB[i0 + p][l]     = cadd(u1, b3);
            SB[i0 + 2 * p][l] = csub(u0, b2);
            SB[i0 + 3 * p][l] = csub(u1, b3);
        }
        __syncthreads();
    }
    #pragma unroll
    for (int itn = 0; itn < 2; ++itn) {
        const int b = bb + (itn << 5);
        const float2 w = tw[b];
        {
            const float2 u = SA[b][l];
            const float2 v = cmul(SA[b + 64][l], w);
            SA[b][l]      = cadd(u, v);
            SA[b + 64][l] = csub(u, v);
        }
        {
            const float2 u = SB[b][l];
            const float2 v = cmul(SB[b + 64][l], w);
            SB[b][l]      = cadd(u, v);
            SB[b + 64][l] = csub(u, v);
        }
    }
}

// ---------------- y-axis forward pass ----------------------------------------
__global__ __launch_bounds__(512) void fft_y_fwd(float2* __restrict__ data) {
    __shared__ float2 s[MESH][LDP];
    __shared__ float2 tw[64];
    const int t = threadIdx.x;
    if (t < 64) {
        float sv, cv;
        sincospif(-(float)t / 64.0f, &sv, &cv);
        tw[t] = make_float2(cv, sv);
    }
    const int outer = blockIdx.x >> 3;
    const int z0 = (blockIdx.x & 7) * TILE;
    const int base = outer * MESH2 + z0;
    for (int i = t; i < MESH * TILE; i += 512) {
        const int l = i & 15, e = i >> 4;
        s[e][l] = data[base + e * MESH + l];
    }
    __syncthreads();
    const int l  = t & 15;
    const int bb = t >> 4;
    fft128_fwd_lds(s, tw, l, bb);
    __syncthreads();
    for (int i = t; i < MESH * TILE; i += 512) {
        const int l2 = i & 15, e = i >> 4;
        data[base + e * MESH + l2] = s[e][l2];
    }
}

// ------- z-forward FFT fused with the staging-tile halo merge (paint flush) --
// ST: 2048 tiles x 1920 floats, tile layout [hx:5][hy:3][z:128].
__global__ __launch_bounds__(512) void fft_z_fwd_merge(const float* __restrict__ ST,
                                                       float2* __restrict__ out) {
    __shared__ float2 s[MESH][LDP];
    __shared__ float2 tw[64];
    const int t = threadIdx.x;
    if (t < 64) {
        float sv, cv;
        sincospif(-(float)t / 64.0f, &sv, &cv);
        tw[t] = make_float2(cv, sv);
    }
    const int col0 = blockIdx.x * TILE;
    const int base = col0 * MESH;
    for (int i = t; i < MESH * TILE; i += 512) {
        const int lc = i >> 7;
        const int z  = i & 127;
        const int c  = col0 + lc;
        const int x = c >> 7, y = c & 127;
        const int tx = x >> 2, ty = y >> 1;
        const int hx = x & 3,  hy = y & 1;
        float v = ST[((tx << 6) | ty) * 1920 + ((hx * 3 + hy) << 7) + z];
        const int txm = (tx + 31) & 31;
        const int tym = (ty + 63) & 63;
        if (hx == 0)
            v += ST[((txm << 6) | ty) * 1920 + ((12 + hy) << 7) + z];
        if (hy == 0) {
            v += ST[((tx << 6) | tym) * 1920 + ((hx * 3 + 2) << 7) + z];
            if (hx == 0)
                v += ST[((txm << 6) | tym) * 1920 + (14 << 7) + z];
        }
        s[z][lc] = make_float2(v, 0.0f);
    }
    __syncthreads();
    const int l  = t & 15;
    const int bb = t >> 4;
    fft128_fwd_lds(s, tw, l, bb);
    __syncthreads();
    for (int i = t; i < MESH * TILE; i += 512)
        out[base + i] = s[i & 127][i >> 7];
}

// ------- fused inverse y + inverse z + bf16 pack, full (y,z) plane in LDS ----
// 256 blocks: [0,128) = A plane x -> Abf bf16x2, [128,256) = B plane x -> Brl.
__global__ __launch_bounds__(1024) void fft_yz_inv_mega(const float2* __restrict__ A,
                                                        const float2* __restrict__ B,
                                                        u32* __restrict__ Abf,
                                                        u16* __restrict__ Brl) {
    __shared__ float2 s[MESH][LDP2];
    __shared__ float2 tw[64];
    const int t = threadIdx.x;
    if (t < 64) {
        float sv, cv;
        sincospif(-(float)t / 64.0f, &sv, &cv);
        tw[t] = make_float2(cv, -sv);     // e^{+i pi m/64}
    }
    const bool isB = blockIdx.x >= 128;
    const int x = blockIdx.x & 127;
    const float2* __restrict__ in = isB ? B : A;
    const int gbase = x * MESH2;
    for (int i = t; i < MESH * MESH; i += 1024)
        s[i >> 7][i & 127] = in[gbase + i];      // s[y][z]
    __syncthreads();

    const int col = t & 127;          // phase-1: z column
    const int wrk = t >> 7;           // [0,8)

    // ---- phase 1: inverse DIT along y (first index) ----
    #pragma unroll
    for (int pr = 0; pr < 3; ++pr) {
        const int st = 2 * pr;
        const int p = 1 << st;
        #pragma unroll
        for (int n = 0; n < 4; ++n) {
            const int bb = wrk | (n << 3);               // [0,32)
            const int j = bb & (p - 1);
            const int g = bb >> st;
            const int i0 = (g << (st + 2)) + j;
            const float2 wA = tw[j << (6 - st)];
            const int mB = j << (5 - st);
            const float2 wB = tw[mB], wB2 = tw[mB + 32];
            const float2 x0 = s[i0][col], x1 = s[i0 + p][col];
            const float2 x2 = s[i0 + 2 * p][col], x3 = s[i0 + 3 * p][col];
            const float2 a1 = cmul(x1, wA), a3 = cmul(x3, wA);
            const float2 u0 = cadd(x0, a1), u1 = csub(x0, a1);
            const float2 u2 = cadd(x2, a3), u3 = csub(x2, a3);
            const float2 b2 = cmul(u2, wB), b3 = cmul(u3, wB2);
            s[i0][col]         = cadd(u0, b2);
            s[i0 + p][col]     = cadd(u1, b3);
            s[i0 + 2 * p][col] = csub(u0, b2);
            s[i0 + 3 * p][col] = csub(u1, b3);
        }
        __syncthreads();
    }
    #pragma unroll
    for (int n = 0; n < 8; ++n) {
        const int b = wrk | (n << 3);                    // [0,64)
        const float2 w = tw[b];
        const float2 u = s[b][col];
        const float2 v = cmul(s[b + 64][col], w);
        s[b][col]      = cadd(u, v);
        s[b + 64][col] = csub(u, v);
    }
    __syncthreads();

    // ---- phase 2: inverse DIT along z (second index) ----
    const int row = t & 127;          // phase-2: y row
    #pragma unroll
    for (int pr = 0; pr < 3; ++pr) {
        const int st = 2 * pr;
        const int p = 1 << st;
        #pragma unroll
        for (int n = 0; n < 4; ++n) {
            const int bb = wrk | (n << 3);
            const int j = bb & (p - 1);
            const int g = bb >> st;
            const int i0 = (g << (st + 2)) + j;
            const float2 wA = tw[j << (6 - st)];
            const int mB = j << (5 - st);
            const float2 wB = tw[mB], wB2 = tw[mB + 32];
            const float2 x0 = s[row][i0], x1 = s[row][i0 + p];
            const float2 x2 = s[row][i0 + 2 * p], x3 = s[row][i0 + 3 * p];
            const float2 a1 = cmul(x1, wA), a3 = cmul(x3, wA);
            const float2 u0 = cadd(x0, a1), u1 = csub(x0, a1);
            const float2 u2 = cadd(x2, a3), u3 = csub(x2, a3);
            const float2 b2 = cmul(u2, wB), b3 = cmul(u3, wB2);
            s[row][i0]         = cadd(u0, b2);
            s[row][i0 + p]     = cadd(u1, b3);
            s[row][i0 + 2 * p] = csub(u0, b2);
            s[row][i0 + 3 * p] = csub(u1, b3);
        }
        __syncthreads();
    }
    #pragma unroll
    for (int n = 0; n < 8; ++n) {
        const int b = wrk | (n << 3);
        const float2 w = tw[b];
        const float2 u = s[row][b];
        const float2 v = cmul(s[row][b + 64], w);
        s[row][b]      = cadd(u, v);
        s[row][b + 64] = csub(u, v);
    }
    __syncthreads();

    if (isB) {
        for (int i = t; i < MESH * MESH; i += 1024)
            Brl[gbase + i] = f2bf(s[i >> 7][i & 127].x);
    } else {
        for (int i = t; i < MESH * MESH; i += 1024) {
            const float2 v = s[i >> 7][i & 127];
            Abf[gbase + i] = (u32)f2bf(v.x) | ((u32)f2bf(v.y) << 16);
        }
    }
}

// Fused: forward x-FFT (DIF) -> filter -> inverse x-FFT (DIT) on A and B lines.
__global__ __launch_bounds__(512) void fft_x_mega(float2* __restrict__ A,
                                                  float2* __restrict__ B) {
    __shared__ float2 SA[MESH][LDP];
    __shared__ float2 SB[MESH][LDP];
    __shared__ float2 twf[64];
    __shared__ float2 twi[64];
    const int t = threadIdx.x;
    if (t < 64) {
        float sv, cv;
        sincospif(-(float)t / 64.0f, &sv, &cv);
        twf[t] = make_float2(cv, sv);
        twi[t] = make_float2(cv, -sv);
    }
    const int cy = blockIdx.x >> 3;
    const int z0 = (blockIdx.x & 7) * TILE;
    const int base = cy * MESH + z0;

    for (int i = t; i < MESH * TILE; i += 512) {
        const int l = i & 15, e = i >> 4;
        SA[e][l] = A[base + e * MESH2 + l];
    }
    __syncthreads();

    const int l  = t & 15;
    const int bb = t >> 4;
    fft128_fwd_lds(SA, twf, l, bb);
    __syncthreads();

    const int jy = (int)(__brev((unsigned)cy) >> 25);
    const float c = 6.28318530717958647692f / 128.0f;
    const float ky = c * (float)(jy < 64 ? jy : jy - 128);
    for (int i = t; i < MESH * TILE; i += 512) {
        const int e = i & 127, ll = i >> 7;
        const int jx = (int)(__brev((unsigned)e) >> 25);
        const int jz = (int)(__brev((unsigned)(z0 + ll)) >> 25);
        const float kx = c * (float)(jx < 64 ? jx : jx - 128);
        const float kz = c * (float)(jz < 64 ? jz : jz - 128);
        const float kk = kx * kx + ky * ky + kz * kz;
        float2 a = SA[e][ll];
        float2 av = make_float2(0.f, 0.f), bv = make_float2(0.f, 0.f);
        if (kk > 0.0f) {
            const float inv_kk = 1.0f / kk;
            const float rng = __expf(-0.09f * inv_kk - kk * kk);  // KL^2=0.09, KS^4=1
            const float sc  = -inv_kk * rng * (1.0f / 2097152.0f);
            const float pr = a.x * sc, pi = a.y * sc;
            av = make_float2(ky * pr + kx * pi, ky * pi - kx * pr);
            bv = make_float2(kz * pi, -kz * pr);
        }
        SA[e][ll] = av;
        SB[e][ll] = bv;
    }
    __syncthreads();

    fft128_inv_lds_dual(SA, SB, twi, l, bb);
    __syncthreads();

    for (int i = t; i < MESH * TILE; i += 512) {
        const int l2 = i & 15, e = i >> 4;
        A[base + e * MESH2 + l2] = SA[e][l2];
        B[base + e * MESH2 + l2] = SB[e][l2];
    }
}

// ---------------- particle binning: 2048 buckets (4x2 columns) ----------------

__device__ __forceinline__ int bucket_of(float px, float py) {
    const int ix = ((int)floorf(px)) & 127;
    const int iy = ((int)floorf(py)) & 127;
    return ((ix >> 2) << 6) | (iy >> 1);
}

__device__ __forceinline__ u64 make_rec(float px, float py, float pz, int n) {
    const float fxx = floorf(px), fyy = floorf(py), fzz = floorf(pz);
    const int ix = ((int)fxx) & 127, iy = ((int)fyy) & 127, iz = ((int)fzz) & 127;
    const u32 qx = (u32)((px - fxx) * 1024.0f);
    const u32 qy = (u32)((py - fyy) * 1024.0f);
    const u32 qz = (u32)((pz - fzz) * 1024.0f);
    return (u64)iz | ((u64)(ix & 3) << 7) | ((u64)(iy & 1) << 9)
         | ((u64)qx << 11) | ((u64)qy << 21) | ((u64)qz << 31)
         | ((u64)(u32)n << 41);
}

// Fused hist+scan+scatter: one pass. Each bucket owns a fixed BSTRIDE region
// of S; a block reserves its span with one global atomicAdd per non-empty
// bucket. Also streams the pos copy to out.
__global__ __launch_bounds__(1024) void bin_kernel(const float* __restrict__ pos,
                                                   u32* __restrict__ gcnt,
                                                   u64* __restrict__ S,
                                                   float4* __restrict__ outp) {
    __shared__ u32 h[2048];
    const int t = threadIdx.x;
    for (int i = t; i < 2048; i += 1024) h[i] = 0;
    __syncthreads();
    const float4* pos4 = (const float4*)pos;
    const int base_q = blockIdx.x * 2048;    // quad index (4 particles each)
    float4 P[2][3];
    #pragma unroll
    for (int it = 0; it < 2; ++it) {
        const int q = base_q + (it << 10) + t;
        const float4 Pa = pos4[3 * q], Pb = pos4[3 * q + 1], Pc = pos4[3 * q + 2];
        P[it][0] = Pa; P[it][1] = Pb; P[it][2] = Pc;
        outp[3 * q]     = Pa;
        outp[3 * q + 1] = Pb;
        outp[3 * q + 2] = Pc;
        atomicAdd(&h[bucket_of(Pa.x, Pa.y)], 1u);
        atomicAdd(&h[bucket_of(Pa.w, Pb.x)], 1u);
        atomicAdd(&h[bucket_of(Pb.z, Pb.w)], 1u);
        atomicAdd(&h[bucket_of(Pc.y, Pc.z)], 1u);
    }
    __syncthreads();
    for (int i = t; i < 2048; i += 1024) {
        const u32 c = h[i];
        h[i] = c ? ((u32)i * BSTRIDE + atomicAdd(&gcnt[i], c)) : 0u;
    }
    __syncthreads();
    #pragma unroll
    for (int it = 0; it < 2; ++it) {
        const int q = base_q + (it << 10) + t;
        const int n = 4 * q;
        const float4 Pa = P[it][0], Pb = P[it][1], Pc = P[it][2];
        S[atomicAdd(&h[bucket_of(Pa.x, Pa.y)], 1u)] = make_rec(Pa.x, Pa.y, Pa.z, n);
        S[atomicAdd(&h[bucket_of(Pa.w, Pb.x)], 1u)] = make_rec(Pa.w, Pb.x, Pb.y, n + 1);
        S[atomicAdd(&h[bucket_of(Pb.z, Pb.w)], 1u)] = make_rec(Pb.z, Pb.w, Pc.x, n + 2);
        S[atomicAdd(&h[bucket_of(Pc.y, Pc.z)], 1u)] = make_rec(Pc.y, Pc.z, Pc.w, n + 3);
    }
}

__device__ __forceinline__ void decode(u64 v, int& iz, int& lx, int& ly,
                                       float& fx, float& fy, float& fz, int& n) {
    iz = (int)(v & 127);
    lx = (int)((v >> 7) & 3);
    ly = (int)((v >> 9) & 3);
    const float inv = 1.0f / 1024.0f;
    fx = (float)((v >> 11) & 1023) * inv;
    fy = (float)((v >> 21) & 1023) * inv;
    fz = (float)((v >> 31) & 1023) * inv;
    n = (int)((v >> 41) & 0x1FFFFF);
}

// GATHER-based paint: bin particles by local cell (1 LDS atomic each), then
// each staging cell gathers from <=8 neighbor cell lists (LDS reads, no atomics).
__global__ __launch_bounds__(512) void paint_kernel(const u64* __restrict__ S,
                                                    const u32* __restrict__ gcnt,
                                                    float* __restrict__ ST) {
    __shared__ u32 cnt[1024];        // per local cell (bx[0..3], by[0..1], bz[0..127])
    __shared__ u32 rec[1024 * CAP];  // qx|qy<<10|qz<<20
    __shared__ u64 ovf[128];
    __shared__ u32 novf;
    const int t = threadIdx.x;
    for (int i = t; i < 1024; i += 512) cnt[i] = 0;
    if (t == 0) novf = 0;
    __syncthreads();
    const int b = blockIdx.x;
    const int start = b * BSTRIDE;
    const int end = start + (int)gcnt[b];
    for (int i = start + t; i < end; i += 512) {
        const u64 v = S[i];
        const int iz = (int)(v & 127);
        const int lx = (int)((v >> 7) & 3);
        const int ly = (int)((v >> 9) & 1);
        const int cell = (((lx << 1) | ly) << 7) | iz;
        const u32 r = (u32)((v >> 11) & 0x3FFFFFFFull);
        const u32 slot = atomicAdd(&cnt[cell], 1u);
        if (slot < CAP) rec[cell * CAP + slot] = r;
        else {
            const u32 o = atomicAdd(&novf, 1u);
            if (o < 128u) ovf[o] = ((u64)cell << 32) | r;
        }
    }
    __syncthreads();
    const u32 nv = novf > 128u ? 128u : novf;
    const float inv = 1.0f / 1024.0f;
    for (int i = t; i < 1920; i += 512) {
        const int hx = i / 384;
        const int hy = (i >> 7) % 3;
        const int z  = i & 127;
        float acc = 0.0f;
        #pragma unroll
        for (int sx = 0; sx < 2; ++sx) {
            const int bx = hx - 1 + sx;            // sx=0 -> dx=1 (weight fx)
            if ((unsigned)bx > 3u) continue;
            #pragma unroll
            for (int sy = 0; sy < 2; ++sy) {
                const int by = hy - 1 + sy;
                if ((unsigned)by > 1u) continue;
                #pragma unroll
                for (int sz = 0; sz < 2; ++sz) {
                    const int bz = (z - 1 + sz) & 127;
                    const int c = (((bx << 1) | by) << 7) | bz;
                    const int m = (int)min(cnt[c], (u32)CAP);
                    const int rb = c * CAP;
                    for (int k = 0; k < m; ++k) {
                        const u32 r = rec[rb + k];
                        const float fx = (float)(r & 1023) * inv;
                        const float fy = (float)((r >> 10) & 1023) * inv;
                        const float fz = (float)(r >> 20) * inv;
                        const float wx = sx ? (1.0f - fx) : fx;
                        const float wy = sy ? (1.0f - fy) : fy;
                        const float wz = sz ? (1.0f - fz) : fz;
                        acc += wx * wy * wz;
                    }
                }
            }
        }
        for (u32 j = 0; j < nv; ++j) {
            const u64 o = ovf[j];
            const int c = (int)(o >> 32);
            const int obx = (c >> 8) & 3, oby = (c >> 7) & 1, obz = c & 127;
            const int dx = hx - obx, dy = hy - oby, dz = (z - obz) & 127;
            if ((unsigned)dx < 2u && (unsigned)dy < 2u && dz < 2) {
                const u32 r = (u32)o;
                const float fx = (float)(r & 1023) * inv;
                const float fy = (float)((r >> 10) & 1023) * inv;
                const float fz = (float)(r >> 20) * inv;
                acc += (dx ? fx : 1.0f - fx) * (dy ? fy : 1.0f - fy)
                     * (dz ? fz : 1.0f - fz);
            }
        }
        ST[(size_t)b * 1920 + i] = acc;
    }
}

// Sorted force readout: field staged as float4 in LDS (one ds_read_b128 per
// corner instead of b64+b32), one scattered 8B store per particle.
__global__ __launch_bounds__(512) void force_kernel(const u64* __restrict__ S,
                                                    const u32* __restrict__ gcnt,
                                                    const u32* __restrict__ Abf,
                                                    const u16* __restrict__ Brl,
                                                    u64* __restrict__ VP) {
    __shared__ float4 sf[1920];      // (gx, gy, gz, unused)
    const int t = threadIdx.x;
    const int b = blockIdx.x;
    const int x0 = (b >> 6) << 2, y0 = (b & 63) << 1;
    for (int i = t; i < 1920; i += 512) {
        const int hx = i / 384;
        const int hy = (i >> 7) % 3;
        const int z = i & 127;
        const int g = (((x0 + hx) & 127) << 14) | (((y0 + hy) & 127) << 7) | z;
        const u32 ab = Abf[g];
        sf[i] = make_float4(__uint_as_float(ab << 16),
                            __uint_as_float(ab & 0xFFFF0000u),
                            bf2f(Brl[g]), 0.0f);
    }
    __syncthreads();
    const int start = b * BSTRIDE;
    const int end = start + (int)gcnt[b];
    for (int i = start + t; i < end; i += 512) {
        int iz, lx, ly, n;
        float fx, fy, fz;
        decode(S[i], iz, lx, ly, fx, fy, fz, n);
        const float wx[2] = {1.0f - fx, fx};
        const float wy[2] = {1.0f - fy, fy};
        const float wz[2] = {1.0f - fz, fz};
        float gx = 0.f, gy = 0.f, gz = 0.f;
        #pragma unroll
        for (int dx = 0; dx < 2; ++dx)
            #pragma unroll
            for (int dy = 0; dy < 2; ++dy) {
                const int bi = ((lx + dx) * 3 + (ly + dy)) << 7;
                const float wxy = wx[dx] * wy[dy];
                #pragma unroll
                for (int dz = 0; dz < 2; ++dz) {
                    const int idx2 = bi + ((iz + dz) & 127);
                    const float w = wxy * wz[dz];
                    const float4 a = sf[idx2];
                    gx += w * a.x;
                    gy += w * a.y;
                    gz += w * a.z;
                }
            }
        VP[n] = (u64)f2bf(gx) | ((u64)f2bf(gy) << 16) | ((u64)f2bf(gz) << 32);
    }
}

// Streaming finalize: out_vel = vel + VP*sc, all coalesced (pos copy in bin).
__global__ __launch_bounds__(256) void finalize_kernel(const float* __restrict__ vel,
                                                       const u64* __restrict__ VP,
                                                       const float* __restrict__ fdf,
                                                       float* __restrict__ out) {
    const int tid = blockIdx.x * 256 + threadIdx.x;   // 524288 threads, 4 particles each
    const float sc = 0.2f / fdf[0];
    const float4* vel4 = (const float4*)vel;
    float4* outv = (float4*)out + (3 * NPART / 4);
    const float4 Va = vel4[3 * tid], Vb = vel4[3 * tid + 1], Vc = vel4[3 * tid + 2];
    const ulonglong2* VP2 = (const ulonglong2*)VP;
    const ulonglong2 qa = VP2[2 * tid];
    const ulonglong2 qb = VP2[2 * tid + 1];
    const u64 q[4] = {qa.x, qa.y, qb.x, qb.y};
    const float vv[12] = {Va.x, Va.y, Va.z, Va.w, Vb.x, Vb.y, Vb.z, Vb.w,
                          Vc.x, Vc.y, Vc.z, Vc.w};
    float ov[12];
    #pragma unroll
    for (int k = 0; k < 4; ++k) {
        const float gx = bf2f((u16)(q[k] & 0xFFFF));
        const float gy = bf2f((u16)((q[k] >> 16) & 0xFFFF));
        const float gz = bf2f((u16)((q[k] >> 32) & 0xFFFF));
        ov[3 * k]     = vv[3 * k]     + gx * sc;
        ov[3 * k + 1] = vv[3 * k + 1] + gy * sc;
        ov[3 * k + 2] = vv[3 * k + 2] + gz * sc;
    }
    outv[3 * tid]     = make_float4(ov[0], ov[1], ov[2], ov[3]);
    outv[3 * tid + 1] = make_float4(ov[4], ov[5], ov[6], ov[7]);
    outv[3 * tid + 2] = make_float4(ov[8], ov[9], ov[10], ov[11]);
}

extern "C" void kernel_launch(void* const* d_in, const int* in_sizes, int n_in,
                              void* d_out, int out_size, void* d_ws, size_t ws_size,
                              hipStream_t stream) {
    const float* pos = (const float*)d_in[0];
    const float* vel = (const float*)d_in[1];
    const float* fdf = (const float*)d_in[2];
    float* out = (float*)d_out;

    // ws layout (16 MiB = 1<<24 per slot):
    //   [0] A grid   [1] B grid   [2] ST staging   [3] Abf + Brl
    //   [4] VP packed forces      [5..6] S bucket regions (25.2 MB)  [7] counters
    char* w = (char*)d_ws;
    float2* A   = (float2*)(w);
    float2* B   = (float2*)(w + ((size_t)1 << 24));
    float*  ST  = (float*)(w + ((size_t)2 << 24));
    u32*    Abf = (u32*)(w + ((size_t)3 << 24));
    u16*    Brl = (u16*)(w + ((size_t)3 << 24) + (size_t)MESH3 * 4);
    u64*    VP  = (u64*)(w + ((size_t)4 << 24));
    u64*    S   = (u64*)(w + ((size_t)5 << 24));   // 2048*1536*8 = 25.2 MB (2 slots)
    u32*    gcnt = (u32*)(w + ((size_t)7 << 24));

    hipMemsetAsync(gcnt, 0, 2048 * sizeof(u32), stream);
    bin_kernel<<<256, 1024, 0, stream>>>(pos, gcnt, S, (float4*)out);

    paint_kernel<<<2048, 512, 0, stream>>>(S, gcnt, ST);

    fft_z_fwd_merge<<<1024, 512, 0, stream>>>(ST, A);   // halo merge + fwd z
    fft_y_fwd<<<1024, 512, 0, stream>>>(A);
    fft_x_mega<<<1024, 512, 0, stream>>>(A, B);         // fwd x + filter + inv x (A,B)
    fft_yz_inv_mega<<<256, 1024, 0, stream>>>(A, B, Abf, Brl);  // inv y + inv z + pack

    force_kernel<<<2048, 512, 0, stream>>>(S, gcnt, Abf, Brl, VP);
    finalize_kernel<<<2048, 256, 0, stream>>>(vel, VP, fdf, out);
}